// Round 6
// baseline (53.711 us; speedup 1.0000x reference)
//
#include <hip/hip_runtime.h>

#define NODES 255
#define IN_DIM 512
#define ODIM 64
#define BM 32

typedef __attribute__((ext_vector_type(8))) short short8v;
typedef __attribute__((ext_vector_type(4))) float f32x4;
typedef unsigned short u16;
typedef unsigned int u32;

__device__ __forceinline__ u16 f32_bf16(float f) {
  u32 u = __builtin_bit_cast(u32, f);
  u += 0x7FFFu + ((u >> 16) & 1u);
  return (u16)(u >> 16);
}
__device__ __forceinline__ float bf16_f32(u16 h) {
  u32 u = ((u32)h) << 16;
  return __builtin_bit_cast(float, u);
}

// Fragment-linear pre-split (same as R5):
//  W: frag(kc 0..15, nb 0..15): elem(lane,j) = W[node=nb*16+(lane&15)][k=kc*32+(lane>>4)*8+j]
//     at linear ((kc*16+nb)*64+lane)*8+j
//  AT: frag(kc4 0..7, nb 0..3): elem(lane,j) = A[leaf=kc4*32+(lane>>4)*8+j][col=nb*16+(lane&15)]
//     at linear ((kc4*4+nb)*64+lane)*8+j
__global__ __launch_bounds__(256) void prep_kernel(
    const float* __restrict__ layers, const float* __restrict__ aprobs,
    u16* __restrict__ Wfh, u16* __restrict__ Wfl,
    u16* __restrict__ ATfh, u16* __restrict__ ATfl) {
  int id = blockIdx.x * 256 + threadIdx.x;
  if (id < 131072) {
    const int j = id & 7;
    const int lane = (id >> 3) & 63;
    const int nb = (id >> 9) & 15;
    const int kc = id >> 13;
    const int node = nb * 16 + (lane & 15);
    const int k = kc * 32 + ((lane >> 4) << 3) + j;
    const float v = (node < NODES) ? layers[node * IN_DIM + k] : 0.f;
    const u16 h = f32_bf16(v);
    Wfh[id] = h;
    Wfl[id] = f32_bf16(v - bf16_f32(h));
  } else if (id < 131072 + 16384) {
    const int t = id - 131072;
    const int j = t & 7;
    const int lane = (t >> 3) & 63;
    const int nb = (t >> 9) & 3;
    const int kc4 = t >> 11;
    const int c = nb * 16 + (lane & 15);
    const int leaf = kc4 * 32 + ((lane >> 4) << 3) + j;
    const float v = aprobs[leaf * ODIM + c];
    const u16 h = f32_bf16(v);
    ATfh[t] = h;
    ATfl[t] = f32_bf16(v - bf16_f32(h));
  }
}

// 512 threads (8 waves), BM=32 rows/block, grid 1024 -> 4 blocks/CU.
// LDS 34,816 B union:
//   phase 1: x dbuf bf16 hi/lo, buf b: hi at b*4096, lo at b*4096+2048 (u16 units), 16 KB
//   phase 2/3: s_sigT f32 [256 nodes][34 rows-pad] = 34,816 B
//   epilogue: sact f32 [32][68] = 8,704 B
__global__ __launch_bounds__(512, 8) void prolo_main(
    const float* __restrict__ x, const float* __restrict__ comp,
    const float* __restrict__ alpha,
    const u16* __restrict__ Wfh, const u16* __restrict__ Wfl,
    const u16* __restrict__ ATfh, const u16* __restrict__ ATfl,
    float* __restrict__ out) {
  __shared__ __align__(16) unsigned char smem[34816];
  float* s_sigT = (float*)smem;  // [256][34]
  u16* sX = (u16*)smem;
  float* sact = (float*)smem;    // [32][68]

  const int tid = threadIdx.x;
  const int lane = tid & 63;
  const int w = tid >> 6;
  const int l15 = lane & 15;
  const int lq = lane >> 4;
  const int row0 = blockIdx.x * BM;
  const float alphav = alpha[0];

  // comparators for this wave's node columns (phase 2)
  const int col0 = (w << 5) + l15;
  const int col1 = col0 + 16;
  const float cv0 = (col0 < NODES) ? comp[col0] : 0.f;
  const float cv1 = (col1 < NODES) ? comp[col1] : 0.f;

  // ---------- Phase 1: z GEMM. Wave w owns nodes [32w,32w+32), rows 0..31.
  f32x4 acc[2][2];
#pragma unroll
  for (int i = 0; i < 2; ++i)
#pragma unroll
    for (int j = 0; j < 2; ++j) acc[i][j] = {0.f, 0.f, 0.f, 0.f};

  const int srow = tid >> 4;          // staging row 0..31
  const int k0 = (tid & 15) << 2;     // staging k 0..60 (4 floats)
  const int soff = srow * 64 + (k0 ^ ((srow & 7) << 3));
  const float* xbase = x + (size_t)(row0 + srow) * IN_DIM + k0;

#define STAGE(V, BUF)                                                        \
  {                                                                          \
    u16 h0 = f32_bf16(V[0]), h1 = f32_bf16(V[1]);                            \
    u16 h2 = f32_bf16(V[2]), h3 = f32_bf16(V[3]);                            \
    u16 e0 = f32_bf16(V[0] - bf16_f32(h0)), e1 = f32_bf16(V[1] - bf16_f32(h1)); \
    u16 e2 = f32_bf16(V[2] - bf16_f32(h2)), e3 = f32_bf16(V[3] - bf16_f32(h3)); \
    u32* dh = reinterpret_cast<u32*>(sX + (BUF)*4096 + soff);                \
    u32* dl = reinterpret_cast<u32*>(sX + (BUF)*4096 + 2048 + soff);         \
    dh[0] = (u32)h0 | ((u32)h1 << 16);                                       \
    dh[1] = (u32)h2 | ((u32)h3 << 16);                                       \
    dl[0] = (u32)e0 | ((u32)e1 << 16);                                       \
    dl[1] = (u32)e2 | ((u32)e3 << 16);                                       \
  }

  f32x4 vA = *reinterpret_cast<const f32x4*>(xbase);
  f32x4 vB = *reinterpret_cast<const f32x4*>(xbase + 64);

  STAGE(vA, 0);
  __syncthreads();

#pragma unroll
  for (int ks = 0; ks < 8; ++ks) {
    if (ks + 2 < 8) vA = *reinterpret_cast<const f32x4*>(xbase + (ks + 2) * 64);
    if (ks + 1 < 8) STAGE(vB, ((ks + 1) & 1));

    const int buf = ks & 1;
#pragma unroll
    for (int kq = 0; kq < 2; ++kq) {
      short8v wbh[2], wbl[2];
#pragma unroll
      for (int ntl = 0; ntl < 2; ++ntl) {
        const int fb = ((((ks << 1) + kq) << 13)) + (w << 10) + (ntl << 9) + (lane << 3);
        wbh[ntl] = *reinterpret_cast<const short8v*>(Wfh + fb);
        wbl[ntl] = *reinterpret_cast<const short8v*>(Wfl + fb);
      }
#pragma unroll
      for (int mt = 0; mt < 2; ++mt) {
        const int r = (mt << 4) + l15;
        const int kk = (kq << 5) + (lq << 3);
        const int aoff = r * 64 + (kk ^ ((r & 7) << 3));
        const short8v ah = *reinterpret_cast<const short8v*>(sX + buf * 4096 + aoff);
        const short8v al = *reinterpret_cast<const short8v*>(sX + buf * 4096 + 2048 + aoff);
#pragma unroll
        for (int ntl = 0; ntl < 2; ++ntl) {
          acc[mt][ntl] = __builtin_amdgcn_mfma_f32_16x16x32_bf16(ah, wbh[ntl], acc[mt][ntl], 0, 0, 0);
          acc[mt][ntl] = __builtin_amdgcn_mfma_f32_16x16x32_bf16(ah, wbl[ntl], acc[mt][ntl], 0, 0, 0);
          acc[mt][ntl] = __builtin_amdgcn_mfma_f32_16x16x32_bf16(al, wbh[ntl], acc[mt][ntl], 0, 0, 0);
        }
      }
    }
    {
      f32x4 t = vA; vA = vB; vB = t;
    }
    __syncthreads();
  }

  // ---------- Phase 2: sigmoid((z-c)*alpha) -> s_sigT[node][row] (pad 34)
#pragma unroll
  for (int ntl = 0; ntl < 2; ++ntl) {
    const int col = (w << 5) + (ntl << 4) + l15;
    const float cv = ntl ? cv1 : cv0;
#pragma unroll
    for (int mt = 0; mt < 2; ++mt) {
#pragma unroll
      for (int r4 = 0; r4 < 4; ++r4) {
        const int r = (mt << 4) + (lq << 2) + r4;
        const float z = (acc[mt][ntl][r4] - cv) * alphav;
        s_sigT[col * 34 + r] = 1.f / (1.f + __expf(-z));
      }
    }
  }
  __syncthreads();

  // ---------- Phase 3+4: in-register leaf probs -> p@A MFMA.
  // Wave w: m-tile mt3 = w>>2 (16 rows), n-tile nt = w&3 (16 cols), full K=256.
  const int mt3 = w >> 2;
  const int nt = w & 3;
  const int arow = (mt3 << 4) + l15;

  f32x4 acc2 = {0.f, 0.f, 0.f, 0.f};

#define SV(node) s_sigT[(node) * 34 + arow]

#pragma unroll
  for (int ks = 0; ks < 8; ++ks) {
    const int lb = (ks << 5) + (lq << 3);
    float P = 1.f;
#pragma unroll
    for (int n = 0; n < 5; ++n) {
      const int node = (1 << n) - 1 + (lb >> (8 - n));
      const float s = SV(node);
      P *= ((lb >> (7 - n)) & 1) ? (1.f - s) : s;
    }
    const float s5 = SV(31 + (lb >> 3));
    const int n6 = 63 + (lb >> 2);
    const float s6a = SV(n6);
    const float s6b = SV(n6 + 1);
    const int n7 = 127 + (lb >> 1);
    const float s7_0 = SV(n7);
    const float s7_1 = SV(n7 + 1);
    const float s7_2 = SV(n7 + 2);
    const float s7_3 = SV(n7 + 3);
    const float q0 = P * s5, q1 = P - P * s5;
    const float r00 = q0 * s6a, r01 = q0 - q0 * s6a;
    const float r10 = q1 * s6b, r11 = q1 - q1 * s6b;
    float p[8];
    p[0] = r00 * s7_0; p[1] = r00 - p[0];
    p[2] = r01 * s7_1; p[3] = r01 - p[2];
    p[4] = r10 * s7_2; p[5] = r10 - p[4];
    p[6] = r11 * s7_3; p[7] = r11 - p[6];
    short8v pah, pal;
#pragma unroll
    for (int j = 0; j < 8; ++j) {
      const u16 h = f32_bf16(p[j]);
      pah[j] = (short)h;
      pal[j] = (short)f32_bf16(p[j] - bf16_f32(h));
    }
    const int fb = (((ks << 2) + nt) << 9) + (lane << 3);
    const short8v bhv = *reinterpret_cast<const short8v*>(ATfh + fb);
    const short8v blv = *reinterpret_cast<const short8v*>(ATfl + fb);
    acc2 = __builtin_amdgcn_mfma_f32_16x16x32_bf16(pah, bhv, acc2, 0, 0, 0);
    acc2 = __builtin_amdgcn_mfma_f32_16x16x32_bf16(pah, blv, acc2, 0, 0, 0);
    acc2 = __builtin_amdgcn_mfma_f32_16x16x32_bf16(pal, bhv, acc2, 0, 0, 0);
  }
  __syncthreads();  // all waves done reading s_sigT

  // exchange actions via sact [32][68] (aliases s_sigT, dead now)
  {
    const int col = (nt << 4) + l15;
#pragma unroll
    for (int r4 = 0; r4 < 4; ++r4) {
      const int r = (mt3 << 4) + (lq << 2) + r4;
      sact[r * 68 + col] = acc2[r4];
    }
  }
  __syncthreads();

  // ---------- Phase 5: softmax + store, waves 0-1 (32 rows).
  if (w < 2) {
#pragma unroll
    for (int r4 = 0; r4 < 4; ++r4) {
      const int rloc = (w << 4) + (lq << 2) + r4;
      const float* ar = sact + rloc * 68;
      float v0 = ar[l15], v1 = ar[16 + l15], v2 = ar[32 + l15], v3 = ar[48 + l15];
      float m = fmaxf(fmaxf(v0, v1), fmaxf(v2, v3));
#pragma unroll
      for (int d = 1; d < 16; d <<= 1) m = fmaxf(m, __shfl_xor(m, d, 64));
      float e0 = __expf(v0 - m), e1 = __expf(v1 - m), e2 = __expf(v2 - m), e3 = __expf(v3 - m);
      float ssum = e0 + e1 + e2 + e3;
#pragma unroll
      for (int d = 1; d < 16; d <<= 1) ssum += __shfl_xor(ssum, d, 64);
      const float inv = 1.f / ssum;
      float* op = out + (size_t)(row0 + rloc) * ODIM + l15;
      op[0] = e0 * inv;
      op[16] = e1 * inv;
      op[32] = e2 * inv;
      op[48] = e3 * inv;
    }
  }
}

extern "C" void kernel_launch(void* const* d_in, const int* in_sizes, int n_in,
                              void* d_out, int out_size, void* d_ws, size_t ws_size,
                              hipStream_t stream) {
  const float* x      = (const float*)d_in[0];
  const float* layers = (const float*)d_in[1];
  const float* comp   = (const float*)d_in[2];
  const float* alpha  = (const float*)d_in[3];
  const float* aprobs = (const float*)d_in[4];
  float* out = (float*)d_out;

  const size_t wsplit = (size_t)131072;
  const size_t atsz   = (size_t)16384;
  if (ws_size < (2 * wsplit + 2 * atsz) * sizeof(u16)) return;

  u16* Wfh  = (u16*)d_ws;
  u16* Wfl  = Wfh + wsplit;
  u16* ATfh = Wfl + wsplit;
  u16* ATfl = ATfh + atsz;

  const int prep_items = 131072 + 16384;
  prep_kernel<<<dim3((prep_items + 255) / 256), dim3(256), 0, stream>>>(
      layers, aprobs, Wfh, Wfl, ATfh, ATfl);

  prolo_main<<<dim3(32768 / BM), dim3(512), 0, stream>>>(
      x, comp, alpha, Wfh, Wfl, ATfh, ATfl, out);
}